// Round 2
// baseline (6940.848 us; speedup 1.0000x reference)
//
#include <hip/hip_runtime.h>
#include <hip/hip_bf16.h>

typedef unsigned short u16;
typedef __attribute__((ext_vector_type(8))) short short8;
typedef __attribute__((ext_vector_type(4))) float floatx4;

#define MTOT 43520   // B*N = 512*85
#define DIMM 512
#define NHEAD 8
#define HD 64

__device__ __forceinline__ float b2f(u16 u) { return __uint_as_float(((unsigned)u) << 16); }
__device__ __forceinline__ u16 f2b(float f) {
  unsigned u = __float_as_uint(f);
  return (u16)((u + 0x7FFFu + ((u >> 16) & 1u)) >> 16);  // RNE; inputs always finite
}

// ---------------- fp32 -> bf16 weight conversion (grid-stride, 4 elems/thread) ----------------
__global__ __launch_bounds__(256) void conv_kernel(const float* __restrict__ in,
                                                   u16* __restrict__ out, int n)
{
  int i = (blockIdx.x * 256 + threadIdx.x) * 4;
  if (i >= n) return;
  float4 v = *(const float4*)(in + i);
  u16 r[4] = { f2b(v.x), f2b(v.y), f2b(v.z), f2b(v.w) };
  *(uint2*)(out + i) = *(uint2*)r;
}

// ---------------- LayerNorm: one wave per 512-wide fp32 row, 4 rows/block ----------------
// OUTF32: 0 -> bf16 out (intermediate h), 1 -> fp32 out (final d_out)
template<int OUTF32>
__global__ __launch_bounds__(256) void ln_kernel(const float* __restrict__ x,
    const float* __restrict__ w, const float* __restrict__ b, void* __restrict__ out)
{
  int row  = blockIdx.x * 4 + (threadIdx.x >> 6);
  int lane = threadIdx.x & 63;
  const float* xr = x + (size_t)row * DIMM;
  float4 a = ((const float4*)xr)[lane * 2];
  float4 c = ((const float4*)xr)[lane * 2 + 1];
  float f[8] = { a.x, a.y, a.z, a.w, c.x, c.y, c.z, c.w };

  float s = 0.f, ss = 0.f;
  #pragma unroll
  for (int i = 0; i < 8; i++) { s += f[i]; ss += f[i] * f[i]; }
  #pragma unroll
  for (int off = 32; off > 0; off >>= 1) {
    s  += __shfl_xor(s,  off);
    ss += __shfl_xor(ss, off);
  }
  float mu  = s * (1.f / 512.f);
  float var = ss * (1.f / 512.f) - mu * mu;
  float rs  = rsqrtf(var + 1e-5f);

  float4 w0 = ((const float4*)w)[lane * 2], w1 = ((const float4*)w)[lane * 2 + 1];
  float4 b0 = ((const float4*)b)[lane * 2], b1 = ((const float4*)b)[lane * 2 + 1];
  float wv[8] = { w0.x, w0.y, w0.z, w0.w, w1.x, w1.y, w1.z, w1.w };
  float bv[8] = { b0.x, b0.y, b0.z, b0.w, b1.x, b1.y, b1.z, b1.w };

  if (OUTF32) {
    float res[8];
    #pragma unroll
    for (int i = 0; i < 8; i++) res[i] = (f[i] - mu) * rs * wv[i] + bv[i];
    float* orow = (float*)out + (size_t)row * DIMM;
    ((float4*)orow)[lane * 2]     = *(float4*)&res[0];
    ((float4*)orow)[lane * 2 + 1] = *(float4*)&res[4];
  } else {
    u16 res[8];
    #pragma unroll
    for (int i = 0; i < 8; i++) res[i] = f2b((f[i] - mu) * rs * wv[i] + bv[i]);
    ((uint4*)((u16*)out + (size_t)row * DIMM))[lane] = *(uint4*)res;
  }
}

// ---------------- GEMM: C[M,Nd] = A[M,K](bf16) @ B[K,Nd](bf16) + bias(f32) ----------------
// EPI: 0 = bias only (bf16 out), 1 = bias + fp32 residual (fp32 out), 2 = bias + exact GELU (bf16 out)
// Tile: BM=128, BN=64, BK=32. 256 threads = 4 waves; wave computes 32x64 via 2x4 MFMA 16x16x32.
template<int EPI>
__global__ __launch_bounds__(256) void gemm_kernel(
    const u16* __restrict__ A, const u16* __restrict__ Bw,
    const float* __restrict__ bias, const float* __restrict__ resid,
    void* __restrict__ Cv, int Nd, int K)
{
  __shared__ u16 As[128 * 40];   // padded stride 40 elems (80B, 16B-aligned)
  __shared__ u16 Bts[64 * 40];   // B transposed: Bt[n][k]

  int t = threadIdx.x;
  int m0 = blockIdx.y * 128, n0 = blockIdx.x * 64;
  int wave = t >> 6, lane = t & 63, quad = lane >> 4, l16 = lane & 15;

  floatx4 zero = {0.f, 0.f, 0.f, 0.f};
  floatx4 acc[2][4];
  #pragma unroll
  for (int mt = 0; mt < 2; mt++)
    #pragma unroll
    for (int nt = 0; nt < 4; nt++) acc[mt][nt] = zero;

  int arow = t >> 1, akg = (t & 1) * 2;   // A: 2 chunks of 8 elems, same row
  int bn = t & 63, bkg = t >> 6;          // B: column bn, k-group bkg (8 k's)

  for (int k0 = 0; k0 < K; k0 += 32) {
    // stage A tile 128x32 (contiguous 16B loads)
    const u16* Ap = A + (size_t)(m0 + arow) * K + k0 + akg * 8;
    uint4 av0 = *(const uint4*)(Ap);
    uint4 av1 = *(const uint4*)(Ap + 8);
    *(uint4*)&As[arow * 40 + akg * 8]     = av0;
    *(uint4*)&As[arow * 40 + akg * 8 + 8] = av1;
    // stage B tile 32x64 transposed (coalesced u16 loads, vector LDS write)
    const u16* Bp = Bw + (size_t)(k0 + bkg * 8) * Nd + n0 + bn;
    u16 tmp[8];
    #pragma unroll
    for (int i = 0; i < 8; i++) tmp[i] = Bp[(size_t)i * Nd];
    *(uint4*)&Bts[bn * 40 + bkg * 8] = *(uint4*)tmp;
    __syncthreads();

    short8 a0 = *(const short8*)&As[(wave * 32 + l16) * 40 + quad * 8];
    short8 a1 = *(const short8*)&As[(wave * 32 + 16 + l16) * 40 + quad * 8];
    #pragma unroll
    for (int nt = 0; nt < 4; nt++) {
      short8 bb = *(const short8*)&Bts[(nt * 16 + l16) * 40 + quad * 8];
      acc[0][nt] = __builtin_amdgcn_mfma_f32_16x16x32_bf16(a0, bb, acc[0][nt], 0, 0, 0);
      acc[1][nt] = __builtin_amdgcn_mfma_f32_16x16x32_bf16(a1, bb, acc[1][nt], 0, 0, 0);
    }
    __syncthreads();
  }

  // epilogue: D row = quad*4+reg, col = l16 (verified gfx950 C/D layout)
  #pragma unroll
  for (int mt = 0; mt < 2; mt++) {
    #pragma unroll
    for (int nt = 0; nt < 4; nt++) {
      int nc = n0 + nt * 16 + l16;
      float bv = bias[nc];
      #pragma unroll
      for (int r = 0; r < 4; r++) {
        int mr = m0 + wave * 32 + mt * 16 + quad * 4 + r;
        size_t idx = (size_t)mr * Nd + nc;
        float v = acc[mt][nt][r] + bv;
        if constexpr (EPI == 1) {
          ((float*)Cv)[idx] = v + resid[idx];
        } else if constexpr (EPI == 2) {
          v = 0.5f * v * (1.f + erff(v * 0.70710678118654752f));
          ((u16*)Cv)[idx] = f2b(v);
        } else {
          ((u16*)Cv)[idx] = f2b(v);
        }
      }
    }
  }
}

// ---------------- Attention (RoPE fused): one block per (batch, head) ----------------
__device__ __forceinline__ int grp(int tk) { return tk == 0 ? 0 : (tk < 5 ? 1 : (tk < 21 ? 2 : 3)); }

__global__ __launch_bounds__(256) void attn_kernel(const u16* __restrict__ qkv,
    const float* __restrict__ coords, u16* __restrict__ out)
{
  __shared__ u16 Qs[85 * 64];
  __shared__ u16 Kts[64 * 128];   // K transposed [d][t]; t>=85 garbage (masked off)
  __shared__ u16 Vs[85 * 64];
  __shared__ float Ps[4 * 96];    // per-wave softmax probabilities

  int b = blockIdx.x >> 3, h = blockIdx.x & 7;
  int tid = threadIdx.x;
  const u16* base = qkv + ((size_t)b * 85) * 1536 + h * 64;

  for (int idx = tid; idx < 85 * 64; idx += 256) {
    int tk = idx >> 6, d = idx & 63;
    const u16* qp = base + (size_t)tk * 1536;
    Vs[tk * 64 + d] = qp[1024 + d];
    float qv, kv;
    if (tk == 0) {
      qv = b2f(qp[d]); kv = b2f(qp[512 + d]);
    } else {
      int j = d & 15, q4 = d >> 4;
      float coord = coords[(tk - 1) * 2 + (q4 >> 1)];
      float freq = __expf((float)j * -0.14391156831212787f);  // -ln(10)/16
      float ang = coord * freq * 6.283185307179586f;
      float sn, cs; __sincosf(ang, &sn, &cs);
      int p0 = ((q4 & 2) << 4) + j, p1 = p0 + 16;
      float a0 = b2f(qp[p0]),       a1 = b2f(qp[p1]);
      float k0 = b2f(qp[512 + p0]), k1 = b2f(qp[512 + p1]);
      if (q4 & 1) { qv = a0 * sn + a1 * cs; kv = k0 * sn + k1 * cs; }
      else        { qv = a0 * cs - a1 * sn; kv = k0 * cs - k1 * sn; }
    }
    Qs[tk * 64 + d]  = f2b(qv);
    Kts[d * 128 + tk] = f2b(kv);
  }
  __syncthreads();

  int wave = tid >> 6, lane = tid & 63;
  const unsigned MBITS = 0x8539u;  // allowed(gr,gc) = (MBITS >> (gr*4+gc)) & 1
  int gc0 = grp(lane);
  int c1 = lane + 64;

  for (int r = wave; r < 85; r += 4) {
    float s0 = 0.f, s1 = 0.f;
    for (int d = 0; d < 64; d++) {
      float qd = b2f(Qs[r * 64 + d]);          // wave-broadcast LDS read
      s0 += qd * b2f(Kts[d * 128 + lane]);
      s1 += qd * b2f(Kts[d * 128 + 64 + lane]);
    }
    int gr = grp(r);
    float m0v = ((MBITS >> (gr * 4 + gc0)) & 1) ? 0.f : -1e30f;
    float m1v = ((MBITS >> (gr * 4 + 3))   & 1) ? 0.f : -1e30f;
    s0 = s0 * 0.125f + m0v;
    s1 = (c1 < 85) ? (s1 * 0.125f + m1v) : -1e30f;

    float mx = fmaxf(s0, s1);
    #pragma unroll
    for (int off = 32; off > 0; off >>= 1) mx = fmaxf(mx, __shfl_xor(mx, off));
    float e0 = __expf(s0 - mx);
    float e1 = (c1 < 85) ? __expf(s1 - mx) : 0.f;
    float sm = e0 + e1;
    #pragma unroll
    for (int off = 32; off > 0; off >>= 1) sm += __shfl_xor(sm, off);
    float inv = 1.f / sm;

    Ps[wave * 96 + lane] = e0 * inv;
    if (c1 < 85) Ps[wave * 96 + c1] = e1 * inv;
    // per-wave LDS RAW: DS pipe is in-order within a wave

    float o = 0.f;
    for (int c = 0; c < 85; c++) o += Ps[wave * 96 + c] * b2f(Vs[c * 64 + lane]);
    out[((size_t)b * 85 + r) * 512 + h * 64 + lane] = f2b(o);
  }
}

extern "C" void kernel_launch(void* const* d_in, const int* in_sizes, int n_in,
                              void* d_out, int out_size, void* d_ws, size_t ws_size,
                              hipStream_t stream) {
  (void)in_sizes; (void)n_in; (void)out_size; (void)ws_size;
  const float* x_in   = (const float*)d_in[0];
  const float* coords = (const float*)d_in[1];
  const float* ln1_w  = (const float*)d_in[2];
  const float* ln1_b  = (const float*)d_in[3];
  const float* qkv_w  = (const float*)d_in[4];
  const float* qkv_b  = (const float*)d_in[5];
  const float* proj_w = (const float*)d_in[6];
  const float* proj_b = (const float*)d_in[7];
  const float* ln2_w  = (const float*)d_in[8];
  const float* ln2_b  = (const float*)d_in[9];
  const float* fc1_w  = (const float*)d_in[10];
  const float* fc1_b  = (const float*)d_in[11];
  const float* fc2_w  = (const float*)d_in[12];
  const float* fc2_b  = (const float*)d_in[13];
  const float* lnf_w  = (const float*)d_in[14];
  const float* lnf_b  = (const float*)d_in[15];

  // workspace layout:
  //   xb   fp32  MTOT*512            (residual stream)       89.1 MB
  //   hb   bf16  MTOT*512            (ln / attn out)         44.6 MB
  //   qb   bf16  MTOT*2048           (qkv / fc1 out)        178.3 MB
  //   wbuf bf16  6*512*(1536+512+2048) + 6*2048*512 weights  37.7 MB
  float* xb = (float*)d_ws;
  u16*   hb = (u16*)(xb + (size_t)MTOT * 512);
  u16*   qb = hb + (size_t)MTOT * 512;
  u16*   wbuf = qb + (size_t)MTOT * 2048;
  u16* wq = wbuf;
  u16* wp = wq + (size_t)6 * 512 * 1536;
  u16* w1 = wp + (size_t)6 * 512 * 512;
  u16* w2 = w1 + (size_t)6 * 512 * 2048;

  dim3 blk(256);
  // convert weights fp32 -> bf16 (every call: same work, graph-safe)
  conv_kernel<<<(6 * 512 * 1536) / 1024, blk, 0, stream>>>(qkv_w, wq, 6 * 512 * 1536);
  conv_kernel<<<(6 * 512 * 512) / 1024, blk, 0, stream>>>(proj_w, wp, 6 * 512 * 512);
  conv_kernel<<<(6 * 512 * 2048) / 1024, blk, 0, stream>>>(fc1_w, w1, 6 * 512 * 2048);
  conv_kernel<<<(6 * 2048 * 512) / 1024, blk, 0, stream>>>(fc2_w, w2, 6 * 2048 * 512);

  for (int l = 0; l < 6; l++) {
    const float* xcur = (l == 0) ? x_in : xb;
    ln_kernel<0><<<MTOT / 4, blk, 0, stream>>>(xcur, ln1_w + l * 512, ln1_b + l * 512, hb);
    gemm_kernel<0><<<dim3(1536 / 64, MTOT / 128), blk, 0, stream>>>(
        hb, wq + (size_t)l * 512 * 1536, qkv_b + (size_t)l * 1536, nullptr, qb, 1536, 512);
    attn_kernel<<<512 * NHEAD, blk, 0, stream>>>(qb, coords, hb);
    gemm_kernel<1><<<dim3(512 / 64, MTOT / 128), blk, 0, stream>>>(
        hb, wp + (size_t)l * 512 * 512, proj_b + (size_t)l * 512, xcur, xb, 512, 512);
    ln_kernel<0><<<MTOT / 4, blk, 0, stream>>>(xb, ln2_w + l * 512, ln2_b + l * 512, hb);
    gemm_kernel<2><<<dim3(2048 / 64, MTOT / 128), blk, 0, stream>>>(
        hb, w1 + (size_t)l * 512 * 2048, fc1_b + (size_t)l * 2048, nullptr, qb, 2048, 512);
    gemm_kernel<1><<<dim3(512 / 64, MTOT / 128), blk, 0, stream>>>(
        qb, w2 + (size_t)l * 2048 * 512, fc2_b + (size_t)l * 512, xb, xb, 512, 2048);
  }
  ln_kernel<1><<<MTOT / 4, blk, 0, stream>>>(xb, lnf_w, lnf_b, d_out);
}

// Round 3
// 4339.117 us; speedup vs baseline: 1.5996x; 1.5996x over previous
//
#include <hip/hip_runtime.h>
#include <hip/hip_bf16.h>

typedef unsigned short u16;
typedef unsigned int u32;
typedef __attribute__((ext_vector_type(8))) short short8;
typedef __attribute__((ext_vector_type(4))) float floatx4;

#define MTOT 43520   // B*N = 512*85
#define DIMM 512
#define NHEAD 8

__device__ __forceinline__ float b2f(u16 u) { return __uint_as_float(((unsigned)u) << 16); }
__device__ __forceinline__ u16 f2b(float f) {
  unsigned u = __float_as_uint(f);
  return (u16)((u + 0x7FFFu + ((u >> 16) & 1u)) >> 16);  // RNE; inputs always finite
}

// async global->LDS, 16B per lane; lds base must be wave-uniform, data lands at base + lane*16
__device__ __forceinline__ void gld16(void* lds, const void* g) {
  __builtin_amdgcn_global_load_lds(
      (const __attribute__((address_space(1))) u32*)g,
      (__attribute__((address_space(3))) u32*)lds, 16, 0, 0);
}

// ---------------- transpose + fp32->bf16: W[K][N] f32 -> Wt[N][K] bf16, per layer z ----------------
__global__ __launch_bounds__(256) void transpose_conv(const float* __restrict__ in,
    u16* __restrict__ out, int K, int N)
{
  const float* W  = in  + (size_t)blockIdx.z * K * N;
  u16*         Wt = out + (size_t)blockIdx.z * K * N;
  int n0 = blockIdx.x * 64, k0 = blockIdx.y * 64;
  int t = threadIdx.x;
  #pragma unroll
  for (int i = 0; i < 2; i++) {
    int task = t + i * 256;          // 512 tasks: 64 n-rows x 8 k-chunks
    int n = task >> 3, kc = (task & 7) * 8;
    u16 tmp[8];
    #pragma unroll
    for (int j = 0; j < 8; j++)
      tmp[j] = f2b(W[(size_t)(k0 + kc + j) * N + n0 + n]);
    *(uint4*)&Wt[(size_t)(n0 + n) * K + k0 + kc] = *(uint4*)tmp;
  }
}

// ---------------- LayerNorm: one wave per 512-wide fp32 row, 4 rows/block ----------------
template<int OUTF32>
__global__ __launch_bounds__(256) void ln_kernel(const float* __restrict__ x,
    const float* __restrict__ w, const float* __restrict__ b, void* __restrict__ out)
{
  int row  = blockIdx.x * 4 + (threadIdx.x >> 6);
  int lane = threadIdx.x & 63;
  const float* xr = x + (size_t)row * DIMM;
  float4 a = ((const float4*)xr)[lane * 2];
  float4 c = ((const float4*)xr)[lane * 2 + 1];
  float f[8] = { a.x, a.y, a.z, a.w, c.x, c.y, c.z, c.w };

  float s = 0.f, ss = 0.f;
  #pragma unroll
  for (int i = 0; i < 8; i++) { s += f[i]; ss += f[i] * f[i]; }
  #pragma unroll
  for (int off = 32; off > 0; off >>= 1) {
    s  += __shfl_xor(s,  off);
    ss += __shfl_xor(ss, off);
  }
  float mu  = s * (1.f / 512.f);
  float var = ss * (1.f / 512.f) - mu * mu;
  float rs  = rsqrtf(var + 1e-5f);

  float4 w0 = ((const float4*)w)[lane * 2], w1 = ((const float4*)w)[lane * 2 + 1];
  float4 b0 = ((const float4*)b)[lane * 2], b1 = ((const float4*)b)[lane * 2 + 1];
  float wv[8] = { w0.x, w0.y, w0.z, w0.w, w1.x, w1.y, w1.z, w1.w };
  float bv[8] = { b0.x, b0.y, b0.z, b0.w, b1.x, b1.y, b1.z, b1.w };

  if (OUTF32) {
    float res[8];
    #pragma unroll
    for (int i = 0; i < 8; i++) res[i] = (f[i] - mu) * rs * wv[i] + bv[i];
    float* orow = (float*)out + (size_t)row * DIMM;
    ((float4*)orow)[lane * 2]     = *(float4*)&res[0];
    ((float4*)orow)[lane * 2 + 1] = *(float4*)&res[4];
  } else {
    u16 res[8];
    #pragma unroll
    for (int i = 0; i < 8; i++) res[i] = f2b((f[i] - mu) * rs * wv[i] + bv[i]);
    ((uint4*)((u16*)out + (size_t)row * DIMM))[lane] = *(uint4*)res;
  }
}

// ---------------- GEMM (m97 pattern): C[M,Nd] = A[M,K] @ Bt[Nd,K]^T + bias ----------------
// EPI: 0 = bias (bf16 out), 1 = bias + fp32 residual (fp32 out), 2 = bias + exact GELU (bf16 out)
template<int EPI>
__global__ __launch_bounds__(256) void gemm_nt(
    const u16* __restrict__ A, const u16* __restrict__ Bt,
    const float* __restrict__ bias, const float* __restrict__ resid,
    void* __restrict__ Cv, int Nd, int K)
{
  __shared__ u16 As[128 * 32];
  __shared__ u16 Bs[128 * 32];

  int t = threadIdx.x;
  int m0 = blockIdx.y * 128, n0 = blockIdx.x * 128;
  int wave = t >> 6, lane = t & 63, quad = lane >> 4, l16 = lane & 15;
  int wr = wave >> 1, wc = wave & 1;

  floatx4 zero = {0.f, 0.f, 0.f, 0.f};
  floatx4 acc[4][4];
  #pragma unroll
  for (int mt = 0; mt < 4; mt++)
    #pragma unroll
    for (int nt = 0; nt < 4; nt++) acc[mt][nt] = zero;

  int srow = wave * 32 + (lane >> 2);   // staging row (+ i*16)
  int kch  = (lane & 3) * 8;            // staging k-chunk (8 elems = 16B)

  for (int k0 = 0; k0 < K; k0 += 32) {
    #pragma unroll
    for (int i = 0; i < 2; i++) {
      int row = srow + i * 16;
      gld16(&As[(wave * 32 + i * 16) * 32], A  + (size_t)(m0 + row) * K + k0 + kch);
      gld16(&Bs[(wave * 32 + i * 16) * 32], Bt + (size_t)(n0 + row) * K + k0 + kch);
    }
    __syncthreads();

    short8 af[4];
    #pragma unroll
    for (int mt = 0; mt < 4; mt++)
      af[mt] = *(const short8*)&As[(wr * 64 + mt * 16 + l16) * 32 + quad * 8];
    #pragma unroll
    for (int nt = 0; nt < 4; nt++) {
      short8 bf = *(const short8*)&Bs[(wc * 64 + nt * 16 + l16) * 32 + quad * 8];
      #pragma unroll
      for (int mt = 0; mt < 4; mt++)
        acc[mt][nt] = __builtin_amdgcn_mfma_f32_16x16x32_bf16(af[mt], bf, acc[mt][nt], 0, 0, 0);
    }
    __syncthreads();
  }

  // epilogue: D row = quad*4+r, col = l16
  #pragma unroll
  for (int mt = 0; mt < 4; mt++) {
    #pragma unroll
    for (int nt = 0; nt < 4; nt++) {
      int nc = n0 + wc * 64 + nt * 16 + l16;
      float bv = bias[nc];
      #pragma unroll
      for (int r = 0; r < 4; r++) {
        int mr = m0 + wr * 64 + mt * 16 + quad * 4 + r;
        size_t idx = (size_t)mr * Nd + nc;
        float v = acc[mt][nt][r] + bv;
        if constexpr (EPI == 1) {
          ((float*)Cv)[idx] = v + resid[idx];
        } else if constexpr (EPI == 2) {
          v = 0.5f * v * (1.f + erff(v * 0.70710678118654752f));
          ((u16*)Cv)[idx] = f2b(v);
        } else {
          ((u16*)Cv)[idx] = f2b(v);
        }
      }
    }
  }
}

// ---------------- MFMA attention (RoPE fused): one block per (batch, head) ----------------
__device__ __forceinline__ int grp(int tk) { return tk == 0 ? 0 : (tk < 5 ? 1 : (tk < 21 ? 2 : 3)); }

__global__ __launch_bounds__(256) void attn_kernel(const u16* __restrict__ qkv,
    const float* __restrict__ coords, u16* __restrict__ out)
{
  __shared__ u16 Qs[96 * 72];   // [token][d], stride 72
  __shared__ u16 Ks[96 * 72];   // [token][d]
  __shared__ u16 Vt[64 * 104];  // [d][token], stride 104
  __shared__ u16 Pb[96 * 104];  // [row][col] softmax probs, bf16

  int b = blockIdx.x >> 3, h = blockIdx.x & 7;
  int tid = threadIdx.x;
  const u16* base = qkv + ((size_t)b * 85) * 1536 + h * 64;

  for (int idx = tid; idx < 96 * 64; idx += 256) {
    int tk = idx >> 6, d = idx & 63;
    float qv = 0.f, kv = 0.f; u16 vv = 0;
    if (tk < 85) {
      const u16* qp = base + (size_t)tk * 1536;
      vv = qp[1024 + d];
      if (tk == 0) {
        qv = b2f(qp[d]); kv = b2f(qp[512 + d]);
      } else {
        int j = d & 15, q4 = d >> 4;
        float coord = coords[(tk - 1) * 2 + (q4 >> 1)];
        float freq = __expf((float)j * -0.14391156831212787f);  // -ln(10)/16
        float ang = coord * freq * 6.283185307179586f;
        float sn, cs; __sincosf(ang, &sn, &cs);
        int p0 = ((q4 & 2) << 4) + j, p1 = p0 + 16;
        float a0 = b2f(qp[p0]),       a1 = b2f(qp[p1]);
        float k0 = b2f(qp[512 + p0]), k1 = b2f(qp[512 + p1]);
        if (q4 & 1) { qv = a0 * sn + a1 * cs; kv = k0 * sn + k1 * cs; }
        else        { qv = a0 * cs - a1 * sn; kv = k0 * cs - k1 * sn; }
      }
    }
    Qs[tk * 72 + d] = f2b(qv);
    Ks[tk * 72 + d] = f2b(kv);
    Vt[d * 104 + tk] = vv;
  }
  __syncthreads();

  int wave = tid >> 6, lane = tid & 63, quad = lane >> 4, l16 = lane & 15;
  const unsigned MBITS = 0x8539u;
  floatx4 zero = {0.f, 0.f, 0.f, 0.f};

  int nb = (wave < 2) ? 2 : 1;     // 6 row-bands of 16 over 4 waves: {0,4},{1,5},{2},{3}
  for (int bi = 0; bi < nb; bi++) {
    int band = (bi == 0) ? wave : wave + 4;

    // S = Q K^T (frag = 8 elems at k = quad*8 + 32*kstep)
    short8 a0 = *(const short8*)&Qs[(band * 16 + l16) * 72 + quad * 8];
    short8 a1 = *(const short8*)&Qs[(band * 16 + l16) * 72 + 32 + quad * 8];
    floatx4 s[6];
    #pragma unroll
    for (int nt = 0; nt < 6; nt++) {
      short8 b0 = *(const short8*)&Ks[(nt * 16 + l16) * 72 + quad * 8];
      short8 b1 = *(const short8*)&Ks[(nt * 16 + l16) * 72 + 32 + quad * 8];
      floatx4 tmp = __builtin_amdgcn_mfma_f32_16x16x32_bf16(a0, b0, zero, 0, 0, 0);
      s[nt] = __builtin_amdgcn_mfma_f32_16x16x32_bf16(a1, b1, tmp, 0, 0, 0);
    }

    int rb = band * 16 + quad * 4;
    #pragma unroll
    for (int r = 0; r < 4; r++) {
      int row = rb + r, gr = grp(row);
      float mx = -3.4e38f;
      #pragma unroll
      for (int nt = 0; nt < 6; nt++) {
        int col = nt * 16 + l16;
        float m = (col < 85 && ((MBITS >> (gr * 4 + grp(col))) & 1)) ? 0.f : -1e30f;
        s[nt][r] = s[nt][r] * 0.125f + m;
        mx = fmaxf(mx, s[nt][r]);
      }
      #pragma unroll
      for (int off = 1; off < 16; off <<= 1) mx = fmaxf(mx, __shfl_xor(mx, off));
      float sum = 0.f;
      #pragma unroll
      for (int nt = 0; nt < 6; nt++) { s[nt][r] = __expf(s[nt][r] - mx); sum += s[nt][r]; }
      #pragma unroll
      for (int off = 1; off < 16; off <<= 1) sum += __shfl_xor(sum, off);
      float inv = 1.f / sum;
      #pragma unroll
      for (int nt = 0; nt < 6; nt++)
        Pb[row * 104 + nt * 16 + l16] = f2b(s[nt][r] * inv);
    }

    // O = P V (in-wave LDS RAW on Pb: wave reads only rows it wrote)
    floatx4 o[4];
    #pragma unroll
    for (int nt2 = 0; nt2 < 4; nt2++) o[nt2] = zero;
    #pragma unroll
    for (int ks = 0; ks < 3; ks++) {
      short8 pa = *(const short8*)&Pb[(band * 16 + l16) * 104 + ks * 32 + quad * 8];
      #pragma unroll
      for (int nt2 = 0; nt2 < 4; nt2++) {
        short8 vb = *(const short8*)&Vt[(nt2 * 16 + l16) * 104 + ks * 32 + quad * 8];
        o[nt2] = __builtin_amdgcn_mfma_f32_16x16x32_bf16(pa, vb, o[nt2], 0, 0, 0);
      }
    }
    #pragma unroll
    for (int nt2 = 0; nt2 < 4; nt2++) {
      #pragma unroll
      for (int r = 0; r < 4; r++) {
        int row = rb + r;
        if (row < 85)
          out[((size_t)b * 85 + row) * 512 + h * 64 + nt2 * 16 + l16] = f2b(o[nt2][r]);
      }
    }
  }
}

extern "C" void kernel_launch(void* const* d_in, const int* in_sizes, int n_in,
                              void* d_out, int out_size, void* d_ws, size_t ws_size,
                              hipStream_t stream) {
  (void)in_sizes; (void)n_in; (void)out_size; (void)ws_size;
  const float* x_in   = (const float*)d_in[0];
  const float* coords = (const float*)d_in[1];
  const float* ln1_w  = (const float*)d_in[2];
  const float* ln1_b  = (const float*)d_in[3];
  const float* qkv_w  = (const float*)d_in[4];
  const float* qkv_b  = (const float*)d_in[5];
  const float* proj_w = (const float*)d_in[6];
  const float* proj_b = (const float*)d_in[7];
  const float* ln2_w  = (const float*)d_in[8];
  const float* ln2_b  = (const float*)d_in[9];
  const float* fc1_w  = (const float*)d_in[10];
  const float* fc1_b  = (const float*)d_in[11];
  const float* fc2_w  = (const float*)d_in[12];
  const float* fc2_b  = (const float*)d_in[13];
  const float* lnf_w  = (const float*)d_in[14];
  const float* lnf_b  = (const float*)d_in[15];

  float* xb = (float*)d_ws;                       // fp32 residual stream
  u16*   hb = (u16*)(xb + (size_t)MTOT * 512);    // bf16 ln/attn buffer
  u16*   qb = hb + (size_t)MTOT * 512;            // bf16 qkv / fc1 buffer
  u16*   wbuf = qb + (size_t)MTOT * 2048;         // transposed bf16 weights
  u16* wq = wbuf;
  u16* wp = wq + (size_t)6 * 512 * 1536;
  u16* w1 = wp + (size_t)6 * 512 * 512;
  u16* w2 = w1 + (size_t)6 * 512 * 2048;

  dim3 blk(256);
  transpose_conv<<<dim3(1536 / 64, 512 / 64, 6), blk, 0, stream>>>(qkv_w, wq, 512, 1536);
  transpose_conv<<<dim3(512 / 64, 512 / 64, 6), blk, 0, stream>>>(proj_w, wp, 512, 512);
  transpose_conv<<<dim3(2048 / 64, 512 / 64, 6), blk, 0, stream>>>(fc1_w, w1, 512, 2048);
  transpose_conv<<<dim3(512 / 64, 2048 / 64, 6), blk, 0, stream>>>(fc2_w, w2, 2048, 512);

  for (int l = 0; l < 6; l++) {
    const float* xcur = (l == 0) ? x_in : xb;
    ln_kernel<0><<<MTOT / 4, blk, 0, stream>>>(xcur, ln1_w + l * 512, ln1_b + l * 512, hb);
    gemm_nt<0><<<dim3(1536 / 128, MTOT / 128), blk, 0, stream>>>(
        hb, wq + (size_t)l * 512 * 1536, qkv_b + (size_t)l * 1536, nullptr, qb, 1536, 512);
    attn_kernel<<<512 * NHEAD, blk, 0, stream>>>(qb, coords, hb);
    gemm_nt<1><<<dim3(512 / 128, MTOT / 128), blk, 0, stream>>>(
        hb, wp + (size_t)l * 512 * 512, proj_b + (size_t)l * 512, xcur, xb, 512, 512);
    ln_kernel<0><<<MTOT / 4, blk, 0, stream>>>(xb, ln2_w + l * 512, ln2_b + l * 512, hb);
    gemm_nt<2><<<dim3(2048 / 128, MTOT / 128), blk, 0, stream>>>(
        hb, w1 + (size_t)l * 512 * 2048, fc1_b + (size_t)l * 2048, nullptr, qb, 2048, 512);
    gemm_nt<1><<<dim3(512 / 128, MTOT / 128), blk, 0, stream>>>(
        qb, w2 + (size_t)l * 2048 * 512, fc2_b + (size_t)l * 512, xb, xb, 512, 2048);
  }
  ln_kernel<1><<<MTOT / 4, blk, 0, stream>>>(xb, lnf_w, lnf_b, d_out);
}